// Round 17
// baseline (245.417 us; speedup 1.0000x reference)
//
#include <hip/hip_runtime.h>
#include <hip/hip_bf16.h>
#include <stdint.h>

#define S 2048
#define D 64
#define BH 32
#define NROWS (BH * S)              // 65536
#define CTX_ELEMS (NROWS * D)
#define NVTB 512                    // VT rider blocks
#define NSTB 2048                   // stream blocks (grid-stride, 4 waves each)
#define VT_BYTES ((size_t)BH * 64 * 64 * 32 * 2)   // 8.4 MB tiled bf16 V^T

typedef __attribute__((ext_vector_type(8))) __bf16 bf16x8;
typedef __attribute__((ext_vector_type(4))) float f32x4;
typedef __attribute__((ext_vector_type(4))) int   i32x4;

// VT32 layout: VT32[bh][kk][c][k']  (kk=k/32, c=col 0..63, k'=k%32); B-frag for
// step kk = one bf16x8; 16 lanes (c=n4*16+l15) x 4 lk cover a contiguous 1KB.

// ---------- Kernel 1: R8 stream, ONE change: PLAIN mask loads (A/B vs nt) ----------
__global__ __launch_bounds__(256) void k_mask(const int* __restrict__ mask,
                                              const float* __restrict__ V,
                                              float* __restrict__ attn,
                                              uint32_t* __restrict__ packed,
                                              __bf16* __restrict__ VT,
                                              int use_vt) {
  const int t = threadIdx.x;

  if (blockIdx.x < NVTB) {
    if (!use_vt) return;
    const int bh = blockIdx.x >> 4;
    const int kk0 = (blockIdx.x & 15) * 4;
    const int c = t >> 2;
    const int g = t & 3;
#pragma unroll
    for (int s = 0; s < 4; ++s) {
      const int kk = kk0 + s;
      const float* vp = V + ((long)bh * S + kk * 32 + g * 8) * D + c;
      bf16x8 o;
#pragma unroll
      for (int j = 0; j < 8; ++j) o[j] = (__bf16)vp[(long)j * D];
      *reinterpret_cast<bf16x8*>(VT + (((long)bh * 64 + kk) * 64 + c) * 32 + g * 8) = o;
    }
    return;
  }

  const int lane = t & 63;
  const int W = (blockIdx.x - NVTB) * 4 + (t >> 6);   // global wave id 0..8191

#pragma unroll 1
  for (int row = W; row < NROWS; row += NSTB * 4) {
    const int* mrow = mask + (long)row * S;

    uint32_t nib = 0;
#pragma unroll
    for (int j = 0; j < 8; ++j) {
      const i32x4 m = *(const i32x4*)(mrow + j * 256 + lane * 4);  // PLAIN load
      nib |= (m[0] == 0 ? 1u : 0u) << (j * 4);
      nib |= (m[1] == 0 ? 1u : 0u) << (j * 4 + 1);
      nib |= (m[2] == 0 ? 1u : 0u) << (j * 4 + 2);
      nib |= (m[3] == 0 ? 1u : 0u) << (j * 4 + 3);
    }

    int cnt = __popc(nib);
#pragma unroll
    for (int off = 1; off < 64; off <<= 1) cnt += __shfl_xor(cnt, off, 64);
    const float inv = (cnt > 0) ? (1.0f / (float)cnt) : 0.0f;

    float* arow = attn + (long)row * S;
#pragma unroll
    for (int j = 0; j < 8; ++j) {
      f32x4 a;
      a[0] = ((nib >> (j * 4)) & 1u)     ? inv : 0.0f;
      a[1] = ((nib >> (j * 4 + 1)) & 1u) ? inv : 0.0f;
      a[2] = ((nib >> (j * 4 + 2)) & 1u) ? inv : 0.0f;
      a[3] = ((nib >> (j * 4 + 3)) & 1u) ? inv : 0.0f;
      __builtin_nontemporal_store(a, (f32x4*)(arow + j * 256 + lane * 4));
    }

    uint32_t word = 0;
    const int jsel = 4 * (lane >> 3);
    const int lbase = (lane & 7) * 8;
#pragma unroll
    for (int d = 0; d < 8; ++d) {
      const uint32_t nw = (uint32_t)__shfl((int)nib, lbase + d, 64);
      word |= ((nw >> jsel) & 0xFu) << (4 * d);
    }
    packed[(long)row * 64 + lane] = word;
  }
}

// ---------- Kernel 2 (R16-VERBATIM): low-traffic AND 2 waves/SIMD ----------
#define BMC 128
template<bool USE_VT>
__global__ __launch_bounds__(256) void k_ctx(const uint32_t* __restrict__ packed,
                                             const float* __restrict__ V,
                                             const __bf16* __restrict__ VT,
                                             float* __restrict__ ctx) {
  // XCD swizzle: each XCD owns 4 whole (b,h) -> VT panel (1MB/XCD) L2-resident
  const int flat = blockIdx.x;
  const int wid = (flat & 7) * ((NROWS / BMC) / 8) + (flat >> 3);
  const int qt = wid & 15;
  const int bh = wid >> 4;

  const int t = threadIdx.x;
  const int lane = t & 63;
  const int w = t >> 6;               // wave 0..3
  const int mh = (w >> 1) * 64;       // m-half row base
  const int nb = (w & 1) * 2;         // n4 pair {nb, nb+1}
  const int l15 = lane & 15;
  const int lk = lane >> 4;           // 0..3

  __shared__ uint32_t pk[BMC * 65];   // byte stride 260 -> bank stride 1
  __shared__ float invs[BMC];

  const long R0 = (long)bh * S + (long)qt * BMC;

  for (int i = t; i < BMC * 64; i += 256)
    pk[(i >> 6) * 65 + (i & 63)] = packed[(R0 + (i >> 6)) * 64 + (i & 63)];
  __syncthreads();

  if (t < BMC) {
    int c = 0;
#pragma unroll
    for (int i = 0; i < 64; ++i) c += __popc(pk[t * 65 + i]);
    invs[t] = (c > 0) ? (1.0f / (float)c) : 0.0f;
  }
  __syncthreads();

  const uint8_t* pkb = (const uint8_t*)pk;
  const uint8_t* ap[4];
#pragma unroll
  for (int mt = 0; mt < 4; ++mt)
    ap[mt] = pkb + (mh + mt * 16 + l15) * 260 + lk;
  const __bf16* vt0 = VT + ((long)bh * 64) * 64 * 32 + (long)l15 * 32 + lk * 8;
  const float* vf0 = V + (long)bh * S * D + (long)lk * 8 * D + l15;

  f32x4 acc[4][2];
#pragma unroll
  for (int a = 0; a < 4; ++a)
#pragma unroll
    for (int b = 0; b < 2; ++b) acc[a][b] = f32x4{0.f, 0.f, 0.f, 0.f};

  auto LOADB = [&](bf16x8* dst, uint32_t* by, int kk) {
    if (USE_VT) {
#pragma unroll
      for (int n = 0; n < 2; ++n)
        dst[n] = *reinterpret_cast<const bf16x8*>(vt0 + ((long)kk * 64 + (nb + n) * 16) * 32);
    } else {
      const float* vp = vf0 + (long)kk * 32 * D;
#pragma unroll
      for (int n = 0; n < 2; ++n) {
        bf16x8 x;
#pragma unroll
        for (int j = 0; j < 8; ++j) x[j] = (__bf16)vp[j * D + (nb + n) * 16];
        dst[n] = x;
      }
    }
#pragma unroll
    for (int mt = 0; mt < 4; ++mt) by[mt] = ap[mt][kk * 4];
  };

  auto COMPUTE = [&](const bf16x8* bf, const uint32_t* by) {
#pragma unroll
    for (int mt = 0; mt < 4; ++mt) {
      union { uint32_t u[4]; bf16x8 v; } am;
#pragma unroll
      for (int p = 0; p < 4; ++p) {
        am.u[p] = (((by[mt] >> (2 * p)) & 1u) ? 0x3F80u : 0u)
                | (((by[mt] >> (2 * p + 1)) & 1u) ? 0x3F800000u : 0u);
      }
#pragma unroll
      for (int n = 0; n < 2; ++n)
        acc[mt][n] = __builtin_amdgcn_mfma_f32_16x16x32_bf16(am.v, bf[n], acc[mt][n], 0, 0, 0);
    }
  };

  bf16x8 bA[2], bB[2];
  uint32_t byA[4], byB[4];
  LOADB(bA, byA, 0);
#pragma unroll 1
  for (int kk = 0; kk < S / 32; kk += 2) {
    LOADB(bB, byB, kk + 1);
    COMPUTE(bA, byA);
    if (kk + 2 < S / 32) LOADB(bA, byA, kk + 2);
    COMPUTE(bB, byB);
  }

  // epilogue: C/D layout col=l15, row=lk*4+ri (m89-verified)
#pragma unroll
  for (int mt = 0; mt < 4; ++mt) {
#pragma unroll
    for (int ri = 0; ri < 4; ++ri) {
      const int rloc = mh + mt * 16 + lk * 4 + ri;
      const float iv = invs[rloc];
      const long orow = R0 + rloc;
#pragma unroll
      for (int n = 0; n < 2; ++n)
        ctx[orow * D + (nb + n) * 16 + l15] = acc[mt][n][ri] * iv;
    }
  }
}

extern "C" void kernel_launch(void* const* d_in, const int* in_sizes, int n_in,
                              void* d_out, int out_size, void* d_ws, size_t ws_size,
                              hipStream_t stream) {
  (void)in_sizes; (void)n_in; (void)out_size;
  const float* V = (const float*)d_in[2];           // Q,K provably unused (mask overwrites all scores)
  const int* mask = (const int*)d_in[3];
  float* ctx = (float*)d_out;                       // output 0: [B,H,S,D]
  float* attn = (float*)d_out + (size_t)CTX_ELEMS;  // output 1: [B,H,S,S]
  uint32_t* packed = (uint32_t*)d_out;              // scratch aliasing ctx region (tile-local)
  __bf16* VT = (__bf16*)d_ws;

  const int use_vt = (ws_size >= VT_BYTES) ? 1 : 0;
  k_mask<<<NVTB + NSTB, 256, 0, stream>>>(mask, V, attn, packed, VT, use_vt);
  if (use_vt)
    k_ctx<true><<<NROWS / BMC, 256, 0, stream>>>(packed, V, VT, ctx);
  else
    k_ctx<false><<<NROWS / BMC, 256, 0, stream>>>(packed, V, VT, ctx);
}

// Round 18
// 232.441 us; speedup vs baseline: 1.0558x; 1.0558x over previous
//
#include <hip/hip_runtime.h>
#include <hip/hip_bf16.h>
#include <stdint.h>

#define S 2048
#define D 64
#define BH 32
#define NROWS (BH * S)              // 65536
#define CTX_ELEMS (NROWS * D)
#define NVTB 512                    // VT rider blocks
#define NSTB 2048                   // stream blocks (grid-stride, 4 waves each)
#define VT_BYTES ((size_t)BH * 64 * 64 * 32 * 2)   // 8.4 MB tiled bf16 V^T

typedef __attribute__((ext_vector_type(8))) __bf16 bf16x8;
typedef __attribute__((ext_vector_type(4))) float f32x4;
typedef __attribute__((ext_vector_type(4))) int   i32x4;

// VT32 layout: VT32[bh][kk][c][k']  (kk=k/32, c=col 0..63, k'=k%32); B-frag for
// step kk = one bf16x8; 16 lanes (c=n4*16+l15) x 4 lk cover a contiguous 1KB.

// ---------- Kernel 1 (R8/R16-VERBATIM): wave-per-row stream + VT riders ----------
// nt mask loads (A/B-verified +13us vs plain, R17) and nt attn stores.
__global__ __launch_bounds__(256) void k_mask(const int* __restrict__ mask,
                                              const float* __restrict__ V,
                                              float* __restrict__ attn,
                                              uint32_t* __restrict__ packed,
                                              __bf16* __restrict__ VT,
                                              int use_vt) {
  const int t = threadIdx.x;

  if (blockIdx.x < NVTB) {
    if (!use_vt) return;
    const int bh = blockIdx.x >> 4;
    const int kk0 = (blockIdx.x & 15) * 4;
    const int c = t >> 2;
    const int g = t & 3;
#pragma unroll
    for (int s = 0; s < 4; ++s) {
      const int kk = kk0 + s;
      const float* vp = V + ((long)bh * S + kk * 32 + g * 8) * D + c;
      bf16x8 o;
#pragma unroll
      for (int j = 0; j < 8; ++j) o[j] = (__bf16)vp[(long)j * D];
      *reinterpret_cast<bf16x8*>(VT + (((long)bh * 64 + kk) * 64 + c) * 32 + g * 8) = o;
    }
    return;
  }

  const int lane = t & 63;
  const int W = (blockIdx.x - NVTB) * 4 + (t >> 6);   // global wave id 0..8191

#pragma unroll 1
  for (int row = W; row < NROWS; row += NSTB * 4) {
    const int* mrow = mask + (long)row * S;

    uint32_t nib = 0;
#pragma unroll
    for (int j = 0; j < 8; ++j) {
      const i32x4 m = __builtin_nontemporal_load(
          (const i32x4*)(mrow + j * 256 + lane * 4));
      nib |= (m[0] == 0 ? 1u : 0u) << (j * 4);
      nib |= (m[1] == 0 ? 1u : 0u) << (j * 4 + 1);
      nib |= (m[2] == 0 ? 1u : 0u) << (j * 4 + 2);
      nib |= (m[3] == 0 ? 1u : 0u) << (j * 4 + 3);
    }

    int cnt = __popc(nib);
#pragma unroll
    for (int off = 1; off < 64; off <<= 1) cnt += __shfl_xor(cnt, off, 64);
    const float inv = (cnt > 0) ? (1.0f / (float)cnt) : 0.0f;

    float* arow = attn + (long)row * S;
#pragma unroll
    for (int j = 0; j < 8; ++j) {
      f32x4 a;
      a[0] = ((nib >> (j * 4)) & 1u)     ? inv : 0.0f;
      a[1] = ((nib >> (j * 4 + 1)) & 1u) ? inv : 0.0f;
      a[2] = ((nib >> (j * 4 + 2)) & 1u) ? inv : 0.0f;
      a[3] = ((nib >> (j * 4 + 3)) & 1u) ? inv : 0.0f;
      __builtin_nontemporal_store(a, (f32x4*)(arow + j * 256 + lane * 4));
    }

    uint32_t word = 0;
    const int jsel = 4 * (lane >> 3);
    const int lbase = (lane & 7) * 8;
#pragma unroll
    for (int d = 0; d < 8; ++d) {
      const uint32_t nw = (uint32_t)__shfl((int)nib, lbase + d, 64);
      word |= ((nw >> jsel) & 0xFu) << (4 * d);
    }
    packed[(long)row * 64 + lane] = word;
  }
}

// ---------- Kernel 2 (R16-VERBATIM): low-traffic AND 2 waves/SIMD ----------
// BMC=128, 256 thr (4 waves). Wave w: M=64 rows [(w>>1)*64,+64) (4 m-tiles
// share each B-frag), N=32 cols [(w&1)*32,+32). 2-deep pipeline; pk stride 260.
#define BMC 128
template<bool USE_VT>
__global__ __launch_bounds__(256) void k_ctx(const uint32_t* __restrict__ packed,
                                             const float* __restrict__ V,
                                             const __bf16* __restrict__ VT,
                                             float* __restrict__ ctx) {
  // XCD swizzle: each XCD owns 4 whole (b,h) -> VT panel (1MB/XCD) L2-resident
  const int flat = blockIdx.x;
  const int wid = (flat & 7) * ((NROWS / BMC) / 8) + (flat >> 3);
  const int qt = wid & 15;
  const int bh = wid >> 4;

  const int t = threadIdx.x;
  const int lane = t & 63;
  const int w = t >> 6;               // wave 0..3
  const int mh = (w >> 1) * 64;       // m-half row base
  const int nb = (w & 1) * 2;         // n4 pair {nb, nb+1}
  const int l15 = lane & 15;
  const int lk = lane >> 4;           // 0..3

  __shared__ uint32_t pk[BMC * 65];   // byte stride 260 -> bank stride 1
  __shared__ float invs[BMC];

  const long R0 = (long)bh * S + (long)qt * BMC;

  for (int i = t; i < BMC * 64; i += 256)
    pk[(i >> 6) * 65 + (i & 63)] = packed[(R0 + (i >> 6)) * 64 + (i & 63)];
  __syncthreads();

  if (t < BMC) {
    int c = 0;
#pragma unroll
    for (int i = 0; i < 64; ++i) c += __popc(pk[t * 65 + i]);
    invs[t] = (c > 0) ? (1.0f / (float)c) : 0.0f;
  }
  __syncthreads();

  const uint8_t* pkb = (const uint8_t*)pk;
  const uint8_t* ap[4];
#pragma unroll
  for (int mt = 0; mt < 4; ++mt)
    ap[mt] = pkb + (mh + mt * 16 + l15) * 260 + lk;
  const __bf16* vt0 = VT + ((long)bh * 64) * 64 * 32 + (long)l15 * 32 + lk * 8;
  const float* vf0 = V + (long)bh * S * D + (long)lk * 8 * D + l15;

  f32x4 acc[4][2];
#pragma unroll
  for (int a = 0; a < 4; ++a)
#pragma unroll
    for (int b = 0; b < 2; ++b) acc[a][b] = f32x4{0.f, 0.f, 0.f, 0.f};

  auto LOADB = [&](bf16x8* dst, uint32_t* by, int kk) {
    if (USE_VT) {
#pragma unroll
      for (int n = 0; n < 2; ++n)
        dst[n] = *reinterpret_cast<const bf16x8*>(vt0 + ((long)kk * 64 + (nb + n) * 16) * 32);
    } else {
      const float* vp = vf0 + (long)kk * 32 * D;
#pragma unroll
      for (int n = 0; n < 2; ++n) {
        bf16x8 x;
#pragma unroll
        for (int j = 0; j < 8; ++j) x[j] = (__bf16)vp[j * D + (nb + n) * 16];
        dst[n] = x;
      }
    }
#pragma unroll
    for (int mt = 0; mt < 4; ++mt) by[mt] = ap[mt][kk * 4];
  };

  auto COMPUTE = [&](const bf16x8* bf, const uint32_t* by) {
#pragma unroll
    for (int mt = 0; mt < 4; ++mt) {
      union { uint32_t u[4]; bf16x8 v; } am;
#pragma unroll
      for (int p = 0; p < 4; ++p) {
        am.u[p] = (((by[mt] >> (2 * p)) & 1u) ? 0x3F80u : 0u)
                | (((by[mt] >> (2 * p + 1)) & 1u) ? 0x3F800000u : 0u);
      }
#pragma unroll
      for (int n = 0; n < 2; ++n)
        acc[mt][n] = __builtin_amdgcn_mfma_f32_16x16x32_bf16(am.v, bf[n], acc[mt][n], 0, 0, 0);
    }
  };

  bf16x8 bA[2], bB[2];
  uint32_t byA[4], byB[4];
  LOADB(bA, byA, 0);
#pragma unroll 1
  for (int kk = 0; kk < S / 32; kk += 2) {
    LOADB(bB, byB, kk + 1);
    COMPUTE(bA, byA);
    if (kk + 2 < S / 32) LOADB(bA, byA, kk + 2);
    COMPUTE(bB, byB);
  }

  // epilogue: C/D layout col=l15, row=lk*4+ri (m89-verified)
#pragma unroll
  for (int mt = 0; mt < 4; ++mt) {
#pragma unroll
    for (int ri = 0; ri < 4; ++ri) {
      const int rloc = mh + mt * 16 + lk * 4 + ri;
      const float iv = invs[rloc];
      const long orow = R0 + rloc;
#pragma unroll
      for (int n = 0; n < 2; ++n)
        ctx[orow * D + (nb + n) * 16 + l15] = acc[mt][n][ri] * iv;
    }
  }
}

extern "C" void kernel_launch(void* const* d_in, const int* in_sizes, int n_in,
                              void* d_out, int out_size, void* d_ws, size_t ws_size,
                              hipStream_t stream) {
  (void)in_sizes; (void)n_in; (void)out_size;
  const float* V = (const float*)d_in[2];           // Q,K provably unused (mask overwrites all scores)
  const int* mask = (const int*)d_in[3];
  float* ctx = (float*)d_out;                       // output 0: [B,H,S,D]
  float* attn = (float*)d_out + (size_t)CTX_ELEMS;  // output 1: [B,H,S,S]
  uint32_t* packed = (uint32_t*)d_out;              // scratch aliasing ctx region (tile-local)
  __bf16* VT = (__bf16*)d_ws;

  const int use_vt = (ws_size >= VT_BYTES) ? 1 : 0;
  k_mask<<<NVTB + NSTB, 256, 0, stream>>>(mask, V, attn, packed, VT, use_vt);
  if (use_vt)
    k_ctx<true><<<NROWS / BMC, 256, 0, stream>>>(packed, V, VT, ctx);
  else
    k_ctx<false><<<NROWS / BMC, 256, 0, stream>>>(packed, V, VT, ctx);
}